// Round 1
// baseline (306.890 us; speedup 1.0000x reference)
//
#include <hip/hip_runtime.h>
#include <math.h>

#define NH   16
#define DK   64
#define SEQL 1024
#define NB   8
#define DIN  1024
#define NKT  (DIN / 64)  // 16 K-tiles of BK=64

typedef __bf16 bf16;
typedef __attribute__((ext_vector_type(8))) __bf16 bf16x8;
typedef __attribute__((ext_vector_type(4))) __bf16 bf16x4;
typedef __attribute__((ext_vector_type(4))) float f32x4;

// fold 1/sqrt(d_k)=1/8 and log2(e) into Q so softmax uses exp2
#define QSCALE 0.18033688011112042f

static __device__ __forceinline__ f32x4 mfma_bf16(bf16x8 a, bf16x8 b, f32x4 c) {
  return __builtin_amdgcn_mfma_f32_16x16x32_bf16(a, b, c, 0, 0, 0);
}

// async global->LDS, 16B per lane. LDS dest = wave-uniform base + lane*16.
static __device__ __forceinline__ void async16(const bf16* g, bf16* l) {
  __builtin_amdgcn_global_load_lds(
      (const __attribute__((address_space(1))) void*)g,
      (__attribute__((address_space(3))) void*)l, 16, 0, 0);
}

// ---------------------------------------------------------------------------
// fp32 -> bf16, 3 tensors per dispatch (blockIdx.y selects), 8 elems/thread
// ---------------------------------------------------------------------------
__global__ __launch_bounds__(256)
void cvt3_kernel(const float* __restrict__ s0, const float* __restrict__ s1,
                 const float* __restrict__ s2, bf16* __restrict__ d0,
                 bf16* __restrict__ d1, bf16* __restrict__ d2, int n8) {
  const int i = blockIdx.x * 256 + threadIdx.x;
  if (i >= n8) return;
  const float* s = (blockIdx.y == 0) ? s0 : (blockIdx.y == 1) ? s1 : s2;
  bf16*        d = (blockIdx.y == 0) ? d0 : (blockIdx.y == 1) ? d1 : d2;
  const f32x4* sp = (const f32x4*)s;
  const f32x4 a = sp[2 * i], b = sp[2 * i + 1];
  bf16x8 r;
  r[0] = (bf16)a[0]; r[1] = (bf16)a[1]; r[2] = (bf16)a[2]; r[3] = (bf16)a[3];
  r[4] = (bf16)b[0]; r[5] = (bf16)b[1]; r[6] = (bf16)b[2]; r[7] = (bf16)b[3];
  ((bf16x8*)d)[i] = r;
}

// ---------------------------------------------------------------------------
// QKV projection GEMM, 256x256 tile, BK=64, 8 waves (2Mx4N), 8-phase-style
// pipelined K-loop with counted vmcnt (never 0 in steady state), raw
// s_barrier, setprio around MFMA clusters. One dispatch, z selects Q/K/V.
// M = nb*1024, N = 1024, K = 1024.
//
// LDS: double-buffered A/B tiles, 128 KiB total. Rows are 128 B; 16-B chunk
// swizzle phys = logical ^ (row&7) applied via pre-swizzled GLOBAL source
// (global_load_lds writes linearly) and the matching XOR on ds_read.
//
// Race-freedom: stage of tile t+2 into buf[t&1] is issued ONLY after a
// barrier preceded by lgkmcnt(0) in phase 3 (all waves' reads of buf[t&1]
// complete). vmcnt(8)+barrier at tile end proves tile t+1 landed for all
// waves while tile t+2's 8 loads stay in flight.
// ---------------------------------------------------------------------------
__global__ __launch_bounds__(512, 2)
void proj_kernel(const bf16* __restrict__ Xq, const bf16* __restrict__ Xk,
                 const bf16* __restrict__ Xv,
                 const bf16* __restrict__ Wq, const bf16* __restrict__ Wk,
                 const bf16* __restrict__ Wv,
                 const float* __restrict__ Bq, const float* __restrict__ Bk,
                 const float* __restrict__ Bv,
                 bf16* __restrict__ Yq, bf16* __restrict__ Yk,
                 bf16* __restrict__ Yv) {
  const int z = blockIdx.z;
  const bf16*  X  = (z == 0) ? Xq : (z == 1) ? Xk : Xv;
  const bf16*  W  = (z == 0) ? Wq : (z == 1) ? Wk : Wv;
  const float* Bi = (z == 0) ? Bq : (z == 1) ? Bk : Bv;
  bf16*        Y  = (z == 0) ? Yq : (z == 1) ? Yk : Yv;

  const int m0 = blockIdx.x * 256;
  const int n0 = blockIdx.y * 256;

  __shared__ __attribute__((aligned(16))) bf16 sA[2][256 * 64];  // 64 KiB
  __shared__ __attribute__((aligned(16))) bf16 sB[2][256 * 64];  // 64 KiB

  const int t    = threadIdx.x;
  const int l    = t & 63;
  const int w    = t >> 6;    // 0..7
  const int l15  = l & 15;
  const int quad = l >> 4;
  const int wm   = w >> 2;    // 0..1 : wave row  (128 rows each)
  const int wn   = w & 3;     // 0..3 : wave col  (64 cols each)
  const int axor = l15 & 7;   // row&7 for all fragment rows (rows = 16*x + l15)

  // staging: per tile, per wave: 4 KiB of A + 4 KiB of B (4 calls each).
  // call c covers LDS rows [(w*4+c)*8, +8); lane l -> row +(l>>3), chunk l&7.
  const int srow = l >> 3;
  const int gcol = ((l & 7) ^ srow) * 8;  // pre-swizzled global k-offset (elems)

  const bf16* Xb = X + (size_t)m0 * DIN;
  const bf16* Wb = W + (size_t)n0 * DIN;

  f32x4 acc[8][4];
#pragma unroll
  for (int i = 0; i < 8; ++i)
#pragma unroll
    for (int j = 0; j < 4; ++j) acc[i][j] = (f32x4){0.f, 0.f, 0.f, 0.f};

#define STAGE(KT, BB)                                                        \
  {                                                                          \
    _Pragma("unroll")                                                        \
    for (int c = 0; c < 4; ++c) {                                            \
      const int rr = w * 32 + c * 8 + srow;                                  \
      async16(Xb + (size_t)rr * DIN + (KT) * 64 + gcol,                      \
              &sA[BB][(w * 4 + c) * 512]);                                   \
      async16(Wb + (size_t)rr * DIN + (KT) * 64 + gcol,                      \
              &sB[BB][(w * 4 + c) * 512]);                                   \
    }                                                                        \
  }

// 12 ds_read_b128 for one C-quadrant: A rows (RH half of wave's 128) x K=64,
// B cols (CH half of wave's 64) x K=64. phys chunk = (kh*4+quad) ^ (row&7).
#define PHASE_READS(RH, CH)                                                  \
  bf16x8 af[4][2], bfr[2][2];                                                \
  _Pragma("unroll")                                                          \
  for (int fi = 0; fi < 4; ++fi) {                                           \
    const int ra = wm * 128 + (RH) * 64 + fi * 16 + l15;                     \
    _Pragma("unroll")                                                        \
    for (int kh = 0; kh < 2; ++kh)                                           \
      af[fi][kh] = *(const bf16x8*)(                                         \
          &sA[b][ra * 64 + ((((kh << 2) | quad) ^ axor) << 3)]);             \
  }                                                                          \
  _Pragma("unroll")                                                          \
  for (int fj = 0; fj < 2; ++fj) {                                           \
    const int rb = wn * 64 + (CH) * 32 + fj * 16 + l15;                      \
    _Pragma("unroll")                                                        \
    for (int kh = 0; kh < 2; ++kh)                                           \
      bfr[fj][kh] = *(const bf16x8*)(                                        \
          &sB[b][rb * 64 + ((((kh << 2) | quad) ^ axor) << 3)]);             \
  }

#define PHASE_MFMA(RH, CH)                                                   \
  _Pragma("unroll")                                                          \
  for (int fi = 0; fi < 4; ++fi)                                             \
    _Pragma("unroll")                                                        \
    for (int fj = 0; fj < 2; ++fj) {                                         \
      acc[(RH) * 4 + fi][(CH) * 2 + fj] = mfma_bf16(                         \
          af[fi][0], bfr[fj][0], acc[(RH) * 4 + fi][(CH) * 2 + fj]);         \
      acc[(RH) * 4 + fi][(CH) * 2 + fj] = mfma_bf16(                         \
          af[fi][1], bfr[fj][1], acc[(RH) * 4 + fi][(CH) * 2 + fj]);         \
    }

#define PHASE(RH, CH)                                                        \
  {                                                                          \
    PHASE_READS(RH, CH)                                                      \
    __builtin_amdgcn_s_barrier();                                            \
    asm volatile("s_waitcnt lgkmcnt(0)" ::: "memory");                       \
    __builtin_amdgcn_sched_barrier(0);                                       \
    __builtin_amdgcn_s_setprio(1);                                           \
    PHASE_MFMA(RH, CH)                                                       \
    __builtin_amdgcn_s_setprio(0);                                           \
    __builtin_amdgcn_s_barrier();                                            \
  }

  // prologue: stage tiles 0 and 1; wait tile 0 (tile 1 stays in flight)
  STAGE(0, 0)
  STAGE(1, 1)
  asm volatile("s_waitcnt vmcnt(8)" ::: "memory");
  __builtin_amdgcn_s_barrier();

  for (int kt = 0; kt < NKT; ++kt) {
    const int b = kt & 1;
    PHASE(0, 0)
    PHASE(0, 1)
    PHASE(1, 0)
    // phase 3: last reads of buf b -> drain -> barrier -> overwrite buf b
    {
      PHASE_READS(1, 1)
      asm volatile("s_waitcnt lgkmcnt(0)" ::: "memory");
      __builtin_amdgcn_s_barrier();  // all waves done READING buf b
      __builtin_amdgcn_sched_barrier(0);
      if (kt < NKT - 2) STAGE(kt + 2, b)
      __builtin_amdgcn_s_setprio(1);
      PHASE_MFMA(1, 1)
      __builtin_amdgcn_s_setprio(0);
      if (kt < NKT - 2) {
        asm volatile("s_waitcnt vmcnt(8)" ::: "memory");  // tile kt+1 landed
      } else if (kt == NKT - 2) {
        asm volatile("s_waitcnt vmcnt(0)" ::: "memory");  // last tile landed
      }
      __builtin_amdgcn_s_barrier();
    }
  }

#undef PHASE
#undef PHASE_MFMA
#undef PHASE_READS
#undef STAGE

  // epilogue: rows = m0 + wm*128 + mi*16 + quad*4 + r, cols = n0 + wn*64 +
  // nj*16 + l15 (MFMA C/D: col=lane&15, row=(lane>>4)*4+reg)
  if (z == 2) {
    // V: transposed [bl, h, d, s] — 4 consecutive s per (mi,nj) -> 8B store
#pragma unroll
    for (int nj = 0; nj < 4; ++nj) {
      const int o    = n0 + wn * 64 + nj * 16 + l15;
      const float bv = Bi[o];
      const int h    = o >> 6;
      const int d    = o & 63;
#pragma unroll
      for (int mi = 0; mi < 8; ++mi) {
        const int m  = m0 + wm * 128 + mi * 16 + quad * 4;
        const int bl = m >> 10;
        const int s  = m & (SEQL - 1);
        bf16x4 pk;
#pragma unroll
        for (int r = 0; r < 4; ++r) pk[r] = (bf16)(acc[mi][nj][r] + bv);
        *(bf16x4*)(Y + ((size_t)(bl * NH + h) * DK + d) * SEQL + s) = pk;
      }
    }
  } else {
    const float scale = (z == 0) ? QSCALE : 1.0f;
#pragma unroll
    for (int nj = 0; nj < 4; ++nj) {
      const int o    = n0 + wn * 64 + nj * 16 + l15;
      const float bv = Bi[o];
      const int h    = o >> 6;
      const int d    = o & 63;
#pragma unroll
      for (int mi = 0; mi < 8; ++mi) {
#pragma unroll
        for (int r = 0; r < 4; ++r) {
          const int m  = m0 + wm * 128 + mi * 16 + quad * 4 + r;
          const int bl = m >> 10;
          const int s  = m & (SEQL - 1);
          Y[(size_t)(((bl * NH + h) << 10) | s) * DK + d] =
              (bf16)((acc[mi][nj][r] + bv) * scale);
        }
      }
    }
  }
}

// ---------------------------------------------------------------------------
// Attention, BK=64: block = (local bh, 128 q-rows), wave owns 32 q (2 groups).
// Computes S^T = K.Q^T so each lane holds 4 consecutive keys -> packed b64
// P-writes; P buffer is per-wave private so no barrier before PV (intra-wave
// lgkmcnt ordering suffices). Exact softmax via exp2 (scale folded into Q);
// denominator via MFMA-with-ones on the rounded P (numerator-consistent).
// ---------------------------------------------------------------------------
__global__ __launch_bounds__(256, 2)
void attn_kernel(const bf16* __restrict__ Q, const bf16* __restrict__ K,
                 const bf16* __restrict__ V, float* __restrict__ Out, int b0) {
  const int bhl = blockIdx.x;        // same-bh blocks share K/V (XCD locality)
  const int q0  = blockIdx.y * 128;
  const int bg  = b0 + (bhl >> 4);
  const int h   = bhl & 15;
  const int t    = threadIdx.x;
  const int l    = t & 63;
  const int w    = t >> 6;
  const int l15  = l & 15;
  const int quad = l >> 4;

  const bf16* Qh = Q + (size_t)bhl * SEQL * DK;
  const bf16* Kh = K + (size_t)bhl * SEQL * DK;
  const bf16* Vh = V + (size_t)bhl * DK * SEQL;  // [d][s]

  __shared__ __attribute__((aligned(16))) bf16 sKs[64 * 64];       // 8 KB
  __shared__ __attribute__((aligned(16))) bf16 sVt[64 * 64];       // 8 KB
  __shared__ __attribute__((aligned(16))) bf16 sPl[4][2][16 * 72]; // 18 KB

  // Q fragments (pre-scaled): lane holds Q[q=l15][d=quad*8+j], 2 d-halves
  bf16x8 qf[2][2];
#pragma unroll
  for (int g = 0; g < 2; ++g)
#pragma unroll
    for (int hh = 0; hh < 2; ++hh)
      qf[g][hh] = *(const bf16x8*)(Qh + (size_t)(q0 + w * 32 + g * 16 + l15) * DK +
                                   hh * 32 + quad * 8);

  bf16x8 ones;
#pragma unroll
  for (int j = 0; j < 8; ++j) ones[j] = (bf16)1.0f;

  f32x4 oacc[2][4];
#pragma unroll
  for (int g = 0; g < 2; ++g)
#pragma unroll
    for (int n = 0; n < 4; ++n) oacc[g][n] = (f32x4){0.f, 0.f, 0.f, 0.f};
  f32x4 sacc[2];
  sacc[0] = (f32x4){0.f, 0.f, 0.f, 0.f};
  sacc[1] = (f32x4){0.f, 0.f, 0.f, 0.f};

  const int drow   = l >> 3;  // DMA: row within 8-row sub-slab
  const int dchunk = l & 7;   // DMA: physical 16B chunk

  for (int kb = 0; kb < SEQL; kb += 64) {
    __syncthreads();  // (A) all waves done reading previous K/V tile
#pragma unroll
    for (int i = 0; i < 2; ++i) {
      const int r = w * 16 + i * 8 + drow;  // tile row 0..63
      async16(Kh + (size_t)(kb + r) * DK + (dchunk ^ (r & 7)) * 8,
              sKs + (w * 16 + i * 8) * 64);
      async16(Vh + (size_t)r * SEQL + kb + (dchunk ^ (r & 7)) * 8,
              sVt + (w * 16 + i * 8) * 64);
    }
    __syncthreads();  // (B) vmcnt(0) drain

    // K fragments: A-operand K[key=c*16+l15][d=hh*32+quad*8+j]
    bf16x8 kf[4][2];
#pragma unroll
    for (int c = 0; c < 4; ++c)
#pragma unroll
      for (int hh = 0; hh < 2; ++hh)
        kf[c][hh] = *(const bf16x8*)(sKs + (c * 16 + l15) * 64 +
                                     (((hh * 4 + quad) ^ (l15 & 7)) * 8));

    // S^T = K.Q^T -> exp2 -> packed b64 P-writes (P stored [q][key], str 72)
#pragma unroll
    for (int g = 0; g < 2; ++g) {
#pragma unroll
      for (int c = 0; c < 4; ++c) {
        f32x4 cs = (f32x4){0.f, 0.f, 0.f, 0.f};
        cs = mfma_bf16(kf[c][0], qf[g][0], cs);
        cs = mfma_bf16(kf[c][1], qf[g][1], cs);
        bf16x4 pk;
#pragma unroll
        for (int r = 0; r < 4; ++r) pk[r] = (bf16)exp2f(cs[r]);
        // lane (quad,l15) holds P[q=l15][keys c*16+quad*4 .. +3]
        *(bf16x4*)(&sPl[w][g][l15 * 72 + c * 16 + quad * 4]) = pk;
      }
    }
    // no barrier: sPl[w] is wave-private; lgkmcnt orders write->read

    // V^T fragments: B-operand V^T[d=n*16+l15][k=hh*32+quad*8+j]
    bf16x8 vfr[4][2];
#pragma unroll
    for (int n = 0; n < 4; ++n)
#pragma unroll
      for (int hh = 0; hh < 2; ++hh)
        vfr[n][hh] = *(const bf16x8*)(sVt + (n * 16 + l15) * 64 +
                                      (((hh * 4 + quad) ^ (l15 & 7)) * 8));
#pragma unroll
    for (int g = 0; g < 2; ++g) {
      const bf16x8 pf0 = *(const bf16x8*)(&sPl[w][g][l15 * 72 + quad * 8]);
      const bf16x8 pf1 = *(const bf16x8*)(&sPl[w][g][l15 * 72 + 32 + quad * 8]);
#pragma unroll
      for (int n = 0; n < 4; ++n) {
        oacc[g][n] = mfma_bf16(pf0, vfr[n][0], oacc[g][n]);
        oacc[g][n] = mfma_bf16(pf1, vfr[n][1], oacc[g][n]);
      }
      sacc[g] = mfma_bf16(pf0, ones, sacc[g]);
      sacc[g] = mfma_bf16(pf1, ones, sacc[g]);
    }
  }

  // epilogue: divide by denominator, write fp32 [b, s, h, d]
#pragma unroll
  for (int g = 0; g < 2; ++g) {
    float linv[4];
#pragma unroll
    for (int r = 0; r < 4; ++r) linv[r] = 1.0f / sacc[g][r];
#pragma unroll
    for (int n = 0; n < 4; ++n) {
      const int d = n * 16 + l15;
#pragma unroll
      for (int r = 0; r < 4; ++r) {
        const int qrow = q0 + w * 32 + g * 16 + quad * 4 + r;
        Out[(size_t)((bg * SEQL + qrow) * NH + h) * DK + d] =
            oacc[g][n][r] * linv[r];
      }
    }
  }
}

extern "C" void kernel_launch(void* const* d_in, const int* in_sizes, int n_in,
                              void* d_out, int out_size, void* d_ws,
                              size_t ws_size, hipStream_t stream) {
  const float* q  = (const float*)d_in[0];
  const float* k  = (const float*)d_in[1];
  const float* v  = (const float*)d_in[2];
  const float* Wq = (const float*)d_in[3];
  const float* bq = (const float*)d_in[4];
  const float* Wk = (const float*)d_in[5];
  const float* bk = (const float*)d_in[6];
  const float* Wv = (const float*)d_in[7];
  const float* bv = (const float*)d_in[8];
  float* out = (float*)d_out;

  // ws layout: [Wq,Wk,Wv bf16: 6MB][Xq,Xk,Xv group][Yq,Yk,Yv group]
  const size_t wElems = (size_t)DIN * DIN;
  const size_t wBytes = 3 * wElems * sizeof(bf16);
  const size_t perBatch = 6 * (size_t)SEQL * DIN * sizeof(bf16);  // 12 MB
  int nbg = (ws_size > wBytes) ? (int)((ws_size - wBytes) / perBatch) : 1;
  if (nbg < 1) nbg = 1;
  if (nbg > NB) nbg = NB;

  bf16* Wqb = (bf16*)d_ws;
  bf16* Wkb = Wqb + wElems;
  bf16* Wvb = Wkb + wElems;
  const size_t g1 = (size_t)nbg * SEQL * DIN;
  bf16* Xqb = Wvb + wElems;
  bf16* Xkb = Xqb + g1;
  bf16* Xvb = Xkb + g1;
  bf16* Yqb = Xvb + g1;
  bf16* Ykb = Yqb + g1;
  bf16* Yvb = Ykb + g1;

  const int w8 = (int)(wElems / 8);
  dim3 gW((w8 + 255) / 256, 3);
  cvt3_kernel<<<gW, 256, 0, stream>>>(Wq, Wk, Wv, Wqb, Wkb, Wvb, w8);

  for (int b0 = 0; b0 < NB; b0 += nbg) {
    const int nb = (NB - b0 < nbg) ? (NB - b0) : nbg;
    const int n8 = nb * SEQL * DIN / 8;
    const size_t xoff = (size_t)b0 * SEQL * DIN;
    dim3 gX((n8 + 255) / 256, 3);
    cvt3_kernel<<<gX, 256, 0, stream>>>(q + xoff, k + xoff, v + xoff,
                                        Xqb, Xkb, Xvb, n8);

    dim3 gP(nb * 4, 4, 3);
    proj_kernel<<<gP, 512, 0, stream>>>(Xqb, Xkb, Xvb, Wqb, Wkb, Wvb,
                                        bq, bk, bv, Yqb, Ykb, Yvb);

    dim3 gA(nb * NH, SEQL / 128);
    attn_kernel<<<gA, 256, 0, stream>>>(Yqb, Ykb, Yvb, out, b0);
  }
}

// Round 2
// 294.984 us; speedup vs baseline: 1.0404x; 1.0404x over previous
//
#include <hip/hip_runtime.h>
#include <math.h>

#define NH   16
#define DK   64
#define SEQL 1024
#define NB   8
#define DIN  1024
#define NKT  (DIN / 64)  // 16 K-tiles of BK=64

typedef __bf16 bf16;
typedef __attribute__((ext_vector_type(8))) __bf16 bf16x8;
typedef __attribute__((ext_vector_type(4))) __bf16 bf16x4;
typedef __attribute__((ext_vector_type(4))) float f32x4;

// fold 1/sqrt(d_k)=1/8 and log2(e) into Q so softmax uses exp2
#define QSCALE 0.18033688011112042f

static __device__ __forceinline__ f32x4 mfma_bf16(bf16x8 a, bf16x8 b, f32x4 c) {
  return __builtin_amdgcn_mfma_f32_16x16x32_bf16(a, b, c, 0, 0, 0);
}

// async global->LDS, 16B per lane. LDS dest = wave-uniform base + lane*16.
static __device__ __forceinline__ void async16(const bf16* g, bf16* l) {
  __builtin_amdgcn_global_load_lds(
      (const __attribute__((address_space(1))) void*)g,
      (__attribute__((address_space(3))) void*)l, 16, 0, 0);
}

// ---------------------------------------------------------------------------
// fp32 -> bf16, 3 tensors per dispatch (blockIdx.y selects), 8 elems/thread
// ---------------------------------------------------------------------------
__global__ __launch_bounds__(256)
void cvt3_kernel(const float* __restrict__ s0, const float* __restrict__ s1,
                 const float* __restrict__ s2, bf16* __restrict__ d0,
                 bf16* __restrict__ d1, bf16* __restrict__ d2, int n8) {
  const int i = blockIdx.x * 256 + threadIdx.x;
  if (i >= n8) return;
  const float* s = (blockIdx.y == 0) ? s0 : (blockIdx.y == 1) ? s1 : s2;
  bf16*        d = (blockIdx.y == 0) ? d0 : (blockIdx.y == 1) ? d1 : d2;
  const f32x4* sp = (const f32x4*)s;
  const f32x4 a = sp[2 * i], b = sp[2 * i + 1];
  bf16x8 r;
  r[0] = (bf16)a[0]; r[1] = (bf16)a[1]; r[2] = (bf16)a[2]; r[3] = (bf16)a[3];
  r[4] = (bf16)b[0]; r[5] = (bf16)b[1]; r[6] = (bf16)b[2]; r[7] = (bf16)b[3];
  ((bf16x8*)d)[i] = r;
}

// ---------------------------------------------------------------------------
// QKV projection GEMM, 256x256 tile, BK=64, 8 waves (2Mx4N), 4-phase zigzag
// K-loop with counted vmcnt (never 0 in steady state), raw s_barrier,
// setprio around MFMA clusters. One dispatch, z selects Q/K/V.
// M = nb*1024, N = 1024, K = 1024.
//
// Phase order (RH,CH): (0,0) -> (0,1) -> (1,1) -> (1,0). Both B-halves are
// held in registers (b0f,b1f) so only A is re-read on the row-half switch:
// ds_read_b128 per K-tile = 12 + 4 + 8 + 0 = 24 (vs 48 for naive quadrants).
// Phase 3 is read-free and hosts the STAGE of tile kt+2 + vmcnt(8).
//
// LDS: double-buffered A/B tiles, 128 KiB total. Rows are 128 B; 16-B chunk
// swizzle phys = logical ^ (row&7) applied via pre-swizzled GLOBAL source
// (global_load_lds writes linearly) and the matching XOR on ds_read.
//
// Race-freedom: the last reads of buf b (phase 2's A1 reads) are complete at
// the phase-2-end barrier (lgkmcnt(0) precedes it), so phase 3 may overwrite
// buf b. vmcnt(8)+barrier at tile end proves tile kt+1 landed for all waves
// while tile kt+2's 8 loads stay in flight.
// ---------------------------------------------------------------------------
__global__ __launch_bounds__(512, 2)
void proj_kernel(const bf16* __restrict__ Xq, const bf16* __restrict__ Xk,
                 const bf16* __restrict__ Xv,
                 const bf16* __restrict__ Wq, const bf16* __restrict__ Wk,
                 const bf16* __restrict__ Wv,
                 const float* __restrict__ Bq, const float* __restrict__ Bk,
                 const float* __restrict__ Bv,
                 bf16* __restrict__ Yq, bf16* __restrict__ Yk,
                 bf16* __restrict__ Yv) {
  const int z = blockIdx.z;
  const bf16*  X  = (z == 0) ? Xq : (z == 1) ? Xk : Xv;
  const bf16*  W  = (z == 0) ? Wq : (z == 1) ? Wk : Wv;
  const float* Bi = (z == 0) ? Bq : (z == 1) ? Bk : Bv;
  bf16*        Y  = (z == 0) ? Yq : (z == 1) ? Yk : Yv;

  const int m0 = blockIdx.x * 256;
  const int n0 = blockIdx.y * 256;

  __shared__ __attribute__((aligned(16))) bf16 sA[2][256 * 64];  // 64 KiB
  __shared__ __attribute__((aligned(16))) bf16 sB[2][256 * 64];  // 64 KiB

  const int t    = threadIdx.x;
  const int l    = t & 63;
  const int w    = t >> 6;    // 0..7
  const int l15  = l & 15;
  const int quad = l >> 4;
  const int wm   = w >> 2;    // 0..1 : wave row  (128 rows each)
  const int wn   = w & 3;     // 0..3 : wave col  (64 cols each)
  const int axor = l15 & 7;   // row&7 for all fragment rows (rows = 16*x + l15)

  // staging: per tile, per wave: 4 KiB of A + 4 KiB of B (4 calls each).
  // call c covers LDS rows [(w*4+c)*8, +8); lane l -> row +(l>>3), chunk l&7.
  const int srow = l >> 3;
  const int gcol = ((l & 7) ^ srow) * 8;  // pre-swizzled global k-offset (elems)

  const bf16* Xb = X + (size_t)m0 * DIN;
  const bf16* Wb = W + (size_t)n0 * DIN;

  f32x4 acc[8][4];
#pragma unroll
  for (int i = 0; i < 8; ++i)
#pragma unroll
    for (int j = 0; j < 4; ++j) acc[i][j] = (f32x4){0.f, 0.f, 0.f, 0.f};

#define STAGE(KT, BB)                                                        \
  {                                                                          \
    _Pragma("unroll")                                                        \
    for (int c = 0; c < 4; ++c) {                                            \
      const int rr = w * 32 + c * 8 + srow;                                  \
      async16(Xb + (size_t)rr * DIN + (KT) * 64 + gcol,                      \
              &sA[BB][(w * 4 + c) * 512]);                                   \
      async16(Wb + (size_t)rr * DIN + (KT) * 64 + gcol,                      \
              &sB[BB][(w * 4 + c) * 512]);                                   \
    }                                                                        \
  }

// 8 ds_read_b128: A fragments for row-half RH (wave's 128 rows) x K=64
#define READ_A(RH)                                                           \
  _Pragma("unroll")                                                          \
  for (int fi = 0; fi < 4; ++fi) {                                           \
    const int ra = wm * 128 + (RH) * 64 + fi * 16 + l15;                     \
    _Pragma("unroll")                                                        \
    for (int kh = 0; kh < 2; ++kh)                                           \
      afr[fi][kh] = *(const bf16x8*)(                                        \
          &sA[b][ra * 64 + ((((kh << 2) | quad) ^ axor) << 3)]);             \
  }

// 4 ds_read_b128: B fragments for col-half CH (wave's 64 cols) x K=64
#define READ_B(DST, CH)                                                      \
  _Pragma("unroll")                                                          \
  for (int fj = 0; fj < 2; ++fj) {                                           \
    const int rb = wn * 64 + (CH) * 32 + fj * 16 + l15;                      \
    _Pragma("unroll")                                                        \
    for (int kh = 0; kh < 2; ++kh)                                           \
      DST[fj][kh] = *(const bf16x8*)(                                        \
          &sB[b][rb * 64 + ((((kh << 2) | quad) ^ axor) << 3)]);             \
  }

// 16 MFMA: one C-quadrant x K=64
#define MFMA_Q(RH, CH, BF)                                                   \
  _Pragma("unroll")                                                          \
  for (int fi = 0; fi < 4; ++fi)                                             \
    _Pragma("unroll")                                                        \
    for (int fj = 0; fj < 2; ++fj) {                                         \
      acc[(RH) * 4 + fi][(CH) * 2 + fj] = mfma_bf16(                         \
          afr[fi][0], BF[fj][0], acc[(RH) * 4 + fi][(CH) * 2 + fj]);         \
      acc[(RH) * 4 + fi][(CH) * 2 + fj] = mfma_bf16(                         \
          afr[fi][1], BF[fj][1], acc[(RH) * 4 + fi][(CH) * 2 + fj]);         \
    }

#define BARRIER_MFMA(RH, CH, BF)                                             \
  __builtin_amdgcn_s_barrier();                                              \
  asm volatile("s_waitcnt lgkmcnt(0)" ::: "memory");                         \
  __builtin_amdgcn_sched_barrier(0);                                         \
  __builtin_amdgcn_s_setprio(1);                                             \
  MFMA_Q(RH, CH, BF)                                                         \
  __builtin_amdgcn_s_setprio(0);                                             \
  __builtin_amdgcn_s_barrier();

  // prologue: stage tiles 0 and 1; wait tile 0 (tile 1 stays in flight)
  STAGE(0, 0)
  STAGE(1, 1)
  asm volatile("s_waitcnt vmcnt(8)" ::: "memory");
  __builtin_amdgcn_s_barrier();

  for (int kt = 0; kt < NKT; ++kt) {
    const int b = kt & 1;
    bf16x8 afr[4][2], b0f[2][2], b1f[2][2];
    // phase 0: (0,0) — read A0 + B0
    READ_A(0)
    READ_B(b0f, 0)
    BARRIER_MFMA(0, 0, b0f)
    // phase 1: (0,1) — read B1, reuse A0
    READ_B(b1f, 1)
    BARRIER_MFMA(0, 1, b1f)
    // phase 2: (1,1) — read A1, reuse B1. After this phase's end barrier,
    // ALL reads of buf b are complete (lgkmcnt(0) preceded it).
    READ_A(1)
    BARRIER_MFMA(1, 1, b1f)
    // phase 3: (1,0) — no reads; stage tile kt+2 into buf b, reuse A1+B0
    if (kt < NKT - 2) STAGE(kt + 2, b)
    __builtin_amdgcn_sched_barrier(0);
    __builtin_amdgcn_s_setprio(1);
    MFMA_Q(1, 0, b0f)
    __builtin_amdgcn_s_setprio(0);
    if (kt < NKT - 2) {
      asm volatile("s_waitcnt vmcnt(8)" ::: "memory");  // tile kt+1 landed
    } else if (kt == NKT - 2) {
      asm volatile("s_waitcnt vmcnt(0)" ::: "memory");  // last tile landed
    }
    __builtin_amdgcn_s_barrier();
  }

#undef BARRIER_MFMA
#undef MFMA_Q
#undef READ_B
#undef READ_A
#undef STAGE

  // epilogue: rows = m0 + wm*128 + mi*16 + quad*4 + r, cols = n0 + wn*64 +
  // nj*16 + l15 (MFMA C/D: col=lane&15, row=(lane>>4)*4+reg)
  if (z == 2) {
    // V: transposed [bl, h, d, s] — 4 consecutive s per (mi,nj) -> 8B store
#pragma unroll
    for (int nj = 0; nj < 4; ++nj) {
      const int o    = n0 + wn * 64 + nj * 16 + l15;
      const float bv = Bi[o];
      const int h    = o >> 6;
      const int d    = o & 63;
#pragma unroll
      for (int mi = 0; mi < 8; ++mi) {
        const int m  = m0 + wm * 128 + mi * 16 + quad * 4;
        const int bl = m >> 10;
        const int s  = m & (SEQL - 1);
        bf16x4 pk;
#pragma unroll
        for (int r = 0; r < 4; ++r) pk[r] = (bf16)(acc[mi][nj][r] + bv);
        *(bf16x4*)(Y + ((size_t)(bl * NH + h) * DK + d) * SEQL + s) = pk;
      }
    }
  } else {
    const float scale = (z == 0) ? QSCALE : 1.0f;
#pragma unroll
    for (int nj = 0; nj < 4; ++nj) {
      const int o    = n0 + wn * 64 + nj * 16 + l15;
      const float bv = Bi[o];
      const int h    = o >> 6;
      const int d    = o & 63;
#pragma unroll
      for (int mi = 0; mi < 8; ++mi) {
#pragma unroll
        for (int r = 0; r < 4; ++r) {
          const int m  = m0 + wm * 128 + mi * 16 + quad * 4 + r;
          const int bl = m >> 10;
          const int s  = m & (SEQL - 1);
          Y[(size_t)(((bl * NH + h) << 10) | s) * DK + d] =
              (bf16)((acc[mi][nj][r] + bv) * scale);
        }
      }
    }
  }
}

// ---------------------------------------------------------------------------
// Attention, BK=64: block = (local bh, 128 q-rows), wave owns 32 q (2 groups).
// Computes S^T = K.Q^T so each lane holds 4 consecutive keys -> packed b64
// P-writes; P buffer is per-wave private so no barrier before PV (intra-wave
// lgkmcnt ordering suffices). Exact softmax via exp2 (scale folded into Q);
// denominator via MFMA-with-ones on the rounded P (numerator-consistent).
// ---------------------------------------------------------------------------
__global__ __launch_bounds__(256, 2)
void attn_kernel(const bf16* __restrict__ Q, const bf16* __restrict__ K,
                 const bf16* __restrict__ V, float* __restrict__ Out, int b0) {
  const int bhl = blockIdx.x;        // same-bh blocks share K/V (XCD locality)
  const int q0  = blockIdx.y * 128;
  const int bg  = b0 + (bhl >> 4);
  const int h   = bhl & 15;
  const int t    = threadIdx.x;
  const int l    = t & 63;
  const int w    = t >> 6;
  const int l15  = l & 15;
  const int quad = l >> 4;

  const bf16* Qh = Q + (size_t)bhl * SEQL * DK;
  const bf16* Kh = K + (size_t)bhl * SEQL * DK;
  const bf16* Vh = V + (size_t)bhl * DK * SEQL;  // [d][s]

  __shared__ __attribute__((aligned(16))) bf16 sKs[64 * 64];       // 8 KB
  __shared__ __attribute__((aligned(16))) bf16 sVt[64 * 64];       // 8 KB
  __shared__ __attribute__((aligned(16))) bf16 sPl[4][2][16 * 72]; // 18 KB

  // Q fragments (pre-scaled): lane holds Q[q=l15][d=quad*8+j], 2 d-halves
  bf16x8 qf[2][2];
#pragma unroll
  for (int g = 0; g < 2; ++g)
#pragma unroll
    for (int hh = 0; hh < 2; ++hh)
      qf[g][hh] = *(const bf16x8*)(Qh + (size_t)(q0 + w * 32 + g * 16 + l15) * DK +
                                   hh * 32 + quad * 8);

  bf16x8 ones;
#pragma unroll
  for (int j = 0; j < 8; ++j) ones[j] = (bf16)1.0f;

  f32x4 oacc[2][4];
#pragma unroll
  for (int g = 0; g < 2; ++g)
#pragma unroll
    for (int n = 0; n < 4; ++n) oacc[g][n] = (f32x4){0.f, 0.f, 0.f, 0.f};
  f32x4 sacc[2];
  sacc[0] = (f32x4){0.f, 0.f, 0.f, 0.f};
  sacc[1] = (f32x4){0.f, 0.f, 0.f, 0.f};

  const int drow   = l >> 3;  // DMA: row within 8-row sub-slab
  const int dchunk = l & 7;   // DMA: physical 16B chunk

  for (int kb = 0; kb < SEQL; kb += 64) {
    __syncthreads();  // (A) all waves done reading previous K/V tile
#pragma unroll
    for (int i = 0; i < 2; ++i) {
      const int r = w * 16 + i * 8 + drow;  // tile row 0..63
      async16(Kh + (size_t)(kb + r) * DK + (dchunk ^ (r & 7)) * 8,
              sKs + (w * 16 + i * 8) * 64);
      async16(Vh + (size_t)r * SEQL + kb + (dchunk ^ (r & 7)) * 8,
              sVt + (w * 16 + i * 8) * 64);
    }
    __syncthreads();  // (B) vmcnt(0) drain

    // K fragments: A-operand K[key=c*16+l15][d=hh*32+quad*8+j]
    bf16x8 kf[4][2];
#pragma unroll
    for (int c = 0; c < 4; ++c)
#pragma unroll
      for (int hh = 0; hh < 2; ++hh)
        kf[c][hh] = *(const bf16x8*)(sKs + (c * 16 + l15) * 64 +
                                     (((hh * 4 + quad) ^ (l15 & 7)) * 8));

    // S^T = K.Q^T -> exp2 -> packed b64 P-writes (P stored [q][key], str 72)
#pragma unroll
    for (int g = 0; g < 2; ++g) {
#pragma unroll
      for (int c = 0; c < 4; ++c) {
        f32x4 cs = (f32x4){0.f, 0.f, 0.f, 0.f};
        cs = mfma_bf16(kf[c][0], qf[g][0], cs);
        cs = mfma_bf16(kf[c][1], qf[g][1], cs);
        bf16x4 pk;
#pragma unroll
        for (int r = 0; r < 4; ++r) pk[r] = (bf16)exp2f(cs[r]);
        // lane (quad,l15) holds P[q=l15][keys c*16+quad*4 .. +3]
        *(bf16x4*)(&sPl[w][g][l15 * 72 + c * 16 + quad * 4]) = pk;
      }
    }
    // no barrier: sPl[w] is wave-private; lgkmcnt orders write->read

    // V^T fragments: B-operand V^T[d=n*16+l15][k=hh*32+quad*8+j]
    bf16x8 vfr[4][2];
#pragma unroll
    for (int n = 0; n < 4; ++n)
#pragma unroll
      for (int hh = 0; hh < 2; ++hh)
        vfr[n][hh] = *(const bf16x8*)(sVt + (n * 16 + l15) * 64 +
                                      (((hh * 4 + quad) ^ (l15 & 7)) * 8));
#pragma unroll
    for (int g = 0; g < 2; ++g) {
      const bf16x8 pf0 = *(const bf16x8*)(&sPl[w][g][l15 * 72 + quad * 8]);
      const bf16x8 pf1 = *(const bf16x8*)(&sPl[w][g][l15 * 72 + 32 + quad * 8]);
#pragma unroll
      for (int n = 0; n < 4; ++n) {
        oacc[g][n] = mfma_bf16(pf0, vfr[n][0], oacc[g][n]);
        oacc[g][n] = mfma_bf16(pf1, vfr[n][1], oacc[g][n]);
      }
      sacc[g] = mfma_bf16(pf0, ones, sacc[g]);
      sacc[g] = mfma_bf16(pf1, ones, sacc[g]);
    }
  }

  // epilogue: divide by denominator, write fp32 [b, s, h, d]
#pragma unroll
  for (int g = 0; g < 2; ++g) {
    float linv[4];
#pragma unroll
    for (int r = 0; r < 4; ++r) linv[r] = 1.0f / sacc[g][r];
#pragma unroll
    for (int n = 0; n < 4; ++n) {
      const int d = n * 16 + l15;
#pragma unroll
      for (int r = 0; r < 4; ++r) {
        const int qrow = q0 + w * 32 + g * 16 + quad * 4 + r;
        Out[(size_t)((bg * SEQL + qrow) * NH + h) * DK + d] =
            oacc[g][n][r] * linv[r];
      }
    }
  }
}

extern "C" void kernel_launch(void* const* d_in, const int* in_sizes, int n_in,
                              void* d_out, int out_size, void* d_ws,
                              size_t ws_size, hipStream_t stream) {
  const float* q  = (const float*)d_in[0];
  const float* k  = (const float*)d_in[1];
  const float* v  = (const float*)d_in[2];
  const float* Wq = (const float*)d_in[3];
  const float* bq = (const float*)d_in[4];
  const float* Wk = (const float*)d_in[5];
  const float* bk = (const float*)d_in[6];
  const float* Wv = (const float*)d_in[7];
  const float* bv = (const float*)d_in[8];
  float* out = (float*)d_out;

  // ws layout: [Wq,Wk,Wv bf16: 6MB][Xq,Xk,Xv group][Yq,Yk,Yv group]
  const size_t wElems = (size_t)DIN * DIN;
  const size_t wBytes = 3 * wElems * sizeof(bf16);
  const size_t perBatch = 6 * (size_t)SEQL * DIN * sizeof(bf16);  // 12 MB
  int nbg = (ws_size > wBytes) ? (int)((ws_size - wBytes) / perBatch) : 1;
  if (nbg < 1) nbg = 1;
  if (nbg > NB) nbg = NB;

  bf16* Wqb = (bf16*)d_ws;
  bf16* Wkb = Wqb + wElems;
  bf16* Wvb = Wkb + wElems;
  const size_t g1 = (size_t)nbg * SEQL * DIN;
  bf16* Xqb = Wvb + wElems;
  bf16* Xkb = Xqb + g1;
  bf16* Xvb = Xkb + g1;
  bf16* Yqb = Xvb + g1;
  bf16* Ykb = Yqb + g1;
  bf16* Yvb = Ykb + g1;

  const int w8 = (int)(wElems / 8);
  dim3 gW((w8 + 255) / 256, 3);
  cvt3_kernel<<<gW, 256, 0, stream>>>(Wq, Wk, Wv, Wqb, Wkb, Wvb, w8);

  for (int b0 = 0; b0 < NB; b0 += nbg) {
    const int nb = (NB - b0 < nbg) ? (NB - b0) : nbg;
    const int n8 = nb * SEQL * DIN / 8;
    const size_t xoff = (size_t)b0 * SEQL * DIN;
    dim3 gX((n8 + 255) / 256, 3);
    cvt3_kernel<<<gX, 256, 0, stream>>>(q + xoff, k + xoff, v + xoff,
                                        Xqb, Xkb, Xvb, n8);

    dim3 gP(nb * 4, 4, 3);
    proj_kernel<<<gP, 512, 0, stream>>>(Xqb, Xkb, Xvb, Wqb, Wkb, Wvb,
                                        bq, bk, bv, Yqb, Ykb, Yvb);

    dim3 gA(nb * NH, SEQL / 128);
    attn_kernel<<<gA, 256, 0, stream>>>(Yqb, Ykb, Yvb, out, b0);
  }
}